// Round 1
// baseline (1576.576 us; speedup 1.0000x reference)
//
#include <hip/hip_runtime.h>
#include <math.h>

#define MT 16
#define NTHREADS 256

// image / grid constants
#define IMG_H 384
#define IMG_W 512
#define H8 48
#define W8 64
#define H16 24
#define W16 32
#define NQ 65536   // queries per batch
#define MTOT 131072 // B * NQ

struct alignas(16) f4 { float v[4]; };

struct Params {
  const float* img; const float* feat_s8; const float* feat_s16;
  const float* coarse_flow; const float* qc;
  const float* pp_w1; const float* pp_b1; const float* pp_w2; const float* pp_b2;
  const float* p8_w; const float* p8_b; const float* p16_w; const float* p16_b;
  const float* f1_ph_w; const float* f1_ph_b; const float* f1_gate;
  const float* f1_w1; const float* f1_b1; const float* f1_w2; const float* f1_b2;
  const float* f1_ln_w; const float* f1_ln_b;
  const float* f2_ph_w; const float* f2_ph_b; const float* f2_gate;
  const float* f2_w1; const float* f2_b1; const float* f2_w2; const float* f2_b2;
  const float* f2_ln_w; const float* f2_ln_b;
  const float* h_w1; const float* h_b1; const float* h_w2; const float* h_b2;
  const float* h_w3; const float* h_b3;
  const float* ft8; const float* ft16;
  float* out;
};

__device__ __forceinline__ float geluf(float x) {
  return 0.5f * x * (1.0f + erff(x * 0.70710678118654752440f));
}
__device__ __forceinline__ float sigm(float x) { return 1.0f / (1.0f + expf(-x)); }

// bilinear on a single [Hd][Wd] plane, align_corners=True + border clamp
__device__ __forceinline__ float bilin_plane(const float* __restrict__ plane,
                                             int Wd, int Hd, float x, float y) {
  x = fminf(fmaxf(x, 0.f), (float)(Wd - 1));
  y = fminf(fmaxf(y, 0.f), (float)(Hd - 1));
  float x0f = floorf(x), y0f = floorf(y);
  int x0 = (int)x0f, y0 = (int)y0f;
  int x1 = min(x0 + 1, Wd - 1), y1 = min(y0 + 1, Hd - 1);
  float wx = x - x0f, wy = y - y0f;
  const float* r0 = plane + y0 * Wd;
  const float* r1 = plane + y1 * Wd;
  float v00 = r0[x0], v01 = r0[x1], v10 = r1[x0], v11 = r1[x1];
  float top = v00 + wx * (v01 - v00);
  float bot = v10 + wx * (v11 - v10);
  return top + wy * (bot - top);
}

// bilinear on channel-last [Hd][Wd][128] features, single channel c
__device__ __forceinline__ float bilin_cl(const float* __restrict__ base,
                                          int Wd, int Hd, float x, float y, int c) {
  x = fminf(fmaxf(x, 0.f), (float)(Wd - 1));
  y = fminf(fmaxf(y, 0.f), (float)(Hd - 1));
  float x0f = floorf(x), y0f = floorf(y);
  int x0 = (int)x0f, y0 = (int)y0f;
  int x1 = min(x0 + 1, Wd - 1), y1 = min(y0 + 1, Hd - 1);
  float wx = x - x0f, wy = y - y0f;
  const float* p00 = base + (y0 * Wd + x0) * 128 + c;
  const float* p01 = base + (y0 * Wd + x1) * 128 + c;
  const float* p10 = base + (y1 * Wd + x0) * 128 + c;
  const float* p11 = base + (y1 * Wd + x1) * 128 + c;
  float v00 = *p00, v01 = *p01, v10 = *p10, v11 = *p11;
  float top = v00 + wx * (v01 - v00);
  float bot = v10 + wx * (v11 - v10);
  return top + wy * (bot - top);
}

// dst[q][nc0+j] = act(bias[nc0+j] + sum_k src[q][k] * Wg[k*ldw + nc0 + j])
// 256 threads: cc = tid&31 -> cols 4cc..4cc+3 of the chunk; qq = tid>>5 -> queries {qq, qq+8}
__device__ void matvec(const float* __restrict__ Wg, const float* __restrict__ Bg,
                       const float* src, int ss, float* dst, int ds,
                       int KI, int KPAD, int NOc, int nc0, int ldw,
                       float* wb, int act) {
  const int tid = threadIdx.x;
  const int cc = tid & 31;
  const int qq = tid >> 5;
  const bool active = (cc << 2) < NOc;
  const int nf4 = NOc >> 2;              // 32 (NOc=128) or 16 (NOc=64)
  const int lsh = (NOc == 128) ? 5 : 4;  // log2(nf4)
  float acc0[4] = {0.f, 0.f, 0.f, 0.f};
  float acc1[4] = {0.f, 0.f, 0.f, 0.f};
  const int nkc = KPAD >> 5;
  for (int kc = 0; kc < nkc; ++kc) {
    __syncthreads();
    const int tot = nf4 << 5;  // 32 rows * nf4 float4 per row
    for (int i = tid; i < tot; i += NTHREADS) {
      int r = i >> lsh;
      int c4 = i & (nf4 - 1);
      int krow = (kc << 5) + r;
      f4 v;
      if (krow < KI) v = *reinterpret_cast<const f4*>(Wg + krow * ldw + nc0 + (c4 << 2));
      else { v.v[0] = 0.f; v.v[1] = 0.f; v.v[2] = 0.f; v.v[3] = 0.f; }
      *reinterpret_cast<f4*>(wb + r * 132 + (c4 << 2)) = v;
    }
    __syncthreads();
    if (active) {
      const float* s0 = src + qq * ss + (kc << 5);
      const float* s1 = src + (qq + 8) * ss + (kc << 5);
#pragma unroll
      for (int k4 = 0; k4 < 8; ++k4) {
        f4 a0 = *reinterpret_cast<const f4*>(s0 + (k4 << 2));
        f4 a1 = *reinterpret_cast<const f4*>(s1 + (k4 << 2));
        const float* wr = wb + (k4 << 2) * 132 + (cc << 2);
#pragma unroll
        for (int r = 0; r < 4; ++r) {
          f4 wv = *reinterpret_cast<const f4*>(wr + r * 132);
          float a0r = a0.v[r], a1r = a1.v[r];
#pragma unroll
          for (int j = 0; j < 4; ++j) {
            acc0[j] = fmaf(a0r, wv.v[j], acc0[j]);
            acc1[j] = fmaf(a1r, wv.v[j], acc1[j]);
          }
        }
      }
    }
  }
  if (active) {
    f4 bv = *reinterpret_cast<const f4*>(Bg + nc0 + (cc << 2));
    f4 o0, o1;
#pragma unroll
    for (int j = 0; j < 4; ++j) {
      float a = acc0[j] + bv.v[j];
      float b = acc1[j] + bv.v[j];
      if (act == 1) { a = geluf(a); b = geluf(b); }
      o0.v[j] = a; o1.v[j] = b;
    }
    *reinterpret_cast<f4*>(dst + qq * ds + nc0 + (cc << 2)) = o0;
    *reinterpret_cast<f4*>(dst + (qq + 8) * ds + nc0 + (cc << 2)) = o1;
  }
}

__device__ void layernorm16(float* hb, const float* __restrict__ lnw,
                            const float* __restrict__ lnb) {
  const int tid = threadIdx.x;
  const int q = tid >> 4;
  const int l = tid & 15;
  float s = 0.f, s2 = 0.f;
  float xs[8];
#pragma unroll
  for (int i = 0; i < 8; ++i) {
    float x = hb[q * 132 + l + i * 16];
    xs[i] = x; s += x; s2 += x * x;
  }
#pragma unroll
  for (int off = 8; off >= 1; off >>= 1) {
    s += __shfl_xor(s, off);
    s2 += __shfl_xor(s2, off);
  }
  float mean = s * 0.0078125f;
  float var = s2 * 0.0078125f - mean * mean;
  float rstd = rsqrtf(var + 1e-5f);
#pragma unroll
  for (int i = 0; i < 8; ++i) {
    int c = l + i * 16;
    hb[q * 132 + c] = (xs[i] - mean) * rstd * lnw[c] + lnb[c];
  }
}

__global__ void transpose_cl(const float* __restrict__ src, float* __restrict__ dst,
                             int Bc, int C, int Hd, int Wd) {
  int total = Bc * C * Hd * Wd;
  for (int i = blockIdx.x * blockDim.x + threadIdx.x; i < total;
       i += gridDim.x * blockDim.x) {
    int x = i % Wd;
    int t = i / Wd;
    int y = t % Hd; t /= Hd;
    int c = t % C;
    int b = t / C;
    dst[((b * Hd + y) * Wd + x) * C + c] = src[i];
  }
}

__global__ __launch_bounds__(NTHREADS) void ifd_fused(Params P) {
  __shared__ __align__(16) float smem[13120];
  float* t0  = smem;          // [16][260]
  float* hb  = smem + 4160;   // [16][132]
  float* t1  = smem + 6272;   // [16][132]
  float* pec = smem + 8384;   // [16][32]  (pe[26], coarse[2])
  float* wb  = smem + 8896;   // [32][132]

  const int tid = threadIdx.x;
  const int m0 = blockIdx.x * MT;

  // ---- P0: sample patches (75), zero pad, coarse (2, scaled), pe (26) ----
  for (int t = tid; t < MT * 128; t += NTHREADS) {
    int q = t >> 7, j = t & 127;
    int m = m0 + q;
    int b = m >> 16;  // NQ = 65536
    float qx = P.qc[m * 2], qy = P.qc[m * 2 + 1];
    if (j < 75) {
      int p = j / 3, ch = j - p * 3;
      int oyi = p / 5 - 2, oxi = p - (p / 5) * 5 - 2;
      const float* plane = P.img + ((b * 3 + ch) * IMG_H) * IMG_W;
      t0[q * 260 + j] = bilin_plane(plane, IMG_W, IMG_H, qx + (float)oxi, qy + (float)oyi);
    } else if (j < 96) {
      t0[q * 260 + j] = 0.f;
    } else if (j < 98) {
      int o = j - 96;
      float x8 = qx * (63.f / 511.f), y8 = qy * (47.f / 383.f);
      const float* plane = P.coarse_flow + (b * 2 + o) * (H8 * W8);
      pec[q * 32 + 26 + o] = 8.f * bilin_plane(plane, W8, H8, x8, y8);
    } else if (j < 124) {
      int jj = j - 98;
      float qx8 = qx * 0.125f, qy8 = qy * 0.125f;
      float lx = (qx8 - rintf(qx8)) * 2.f;
      float ly = (qy8 - rintf(qy8)) * 2.f;
      if (jj < 2) {
        pec[q * 32 + jj] = jj ? ly : lx;
      } else {
        int k = jj - 2;
        int dim = k / 12;
        int tt = k - dim * 12;
        int band = tt % 6, iscos = tt / 6;
        float loc = dim ? ly : lx;
        float ang = loc * 3.14159265358979323846f * (float)(1 << band);
        pec[q * 32 + 2 + k] = iscos ? cosf(ang) : sinf(ang);
      }
    }
  }

  // S1: t1 = gelu(patches @ pp_w1 + pp_b1)   [75->128]
  matvec(P.pp_w1, P.pp_b1, t0, 260, t1, 132, 75, 96, 128, 0, 128, wb, 1);
  // S2: hb = t1 @ pp_w2 + pp_b2              [128->128]  (h = f_local)
  matvec(P.pp_w2, P.pp_b2, t1, 132, hb, 132, 128, 128, 128, 0, 128, wb, 0);

  // S3: sample feat_s8 (channel-last) -> t0
  for (int t = tid; t < MT * 128; t += NTHREADS) {
    int q = t >> 7, c = t & 127;
    int m = m0 + q;
    int b = m >> 16;
    float qx = P.qc[m * 2], qy = P.qc[m * 2 + 1];
    float x8 = qx * (63.f / 511.f), y8 = qy * (47.f / 383.f);
    t0[q * 260 + c] = bilin_cl(P.ft8 + b * (H8 * W8 * 128), W8, H8, x8, y8, c);
  }

  // S4: t1 = f8 = t0 @ p8_w + p8_b
  matvec(P.p8_w, P.p8_b, t0, 260, t1, 132, 128, 128, 128, 0, 128, wb, 0);
  // S5: t0 = hb @ f1_ph_w + f1_ph_b
  matvec(P.f1_ph_w, P.f1_ph_b, hb, 132, t0, 260, 128, 128, 128, 0, 128, wb, 0);

  // S6: fuse: t1 = t1 + sigmoid(f1_gate) * t0
  __syncthreads();
  for (int t = tid; t < MT * 128; t += NTHREADS) {
    int q = t >> 7, c = t & 127;
    t1[q * 132 + c] += sigm(P.f1_gate[c]) * t0[q * 260 + c];
  }

  // S7: t0[0:256] = gelu(t1 @ f1_w1 + f1_b1)  [128->256]
  matvec(P.f1_w1, P.f1_b1, t1, 132, t0, 260, 128, 128, 128, 0, 256, wb, 1);
  matvec(P.f1_w1, P.f1_b1, t1, 132, t0, 260, 128, 128, 128, 128, 256, wb, 1);
  // S8: hb = t0 @ f1_w2 + f1_b2               [256->128]
  matvec(P.f1_w2, P.f1_b2, t0, 260, hb, 132, 256, 256, 128, 0, 128, wb, 0);

  // S9: layernorm(hb) with f1_ln
  __syncthreads();
  layernorm16(hb, P.f1_ln_w, P.f1_ln_b);
  __syncthreads();

  // S10: sample feat_s16 -> t0
  for (int t = tid; t < MT * 128; t += NTHREADS) {
    int q = t >> 7, c = t & 127;
    int m = m0 + q;
    int b = m >> 16;
    float qx = P.qc[m * 2], qy = P.qc[m * 2 + 1];
    float x16 = qx * (31.f / 511.f), y16 = qy * (23.f / 383.f);
    t0[q * 260 + c] = bilin_cl(P.ft16 + b * (H16 * W16 * 128), W16, H16, x16, y16, c);
  }

  // S11: t1 = f16 = t0 @ p16_w + p16_b
  matvec(P.p16_w, P.p16_b, t0, 260, t1, 132, 128, 128, 128, 0, 128, wb, 0);
  // S12: t0 = hb @ f2_ph_w + f2_ph_b
  matvec(P.f2_ph_w, P.f2_ph_b, hb, 132, t0, 260, 128, 128, 128, 0, 128, wb, 0);

  // S13: fuse with f2_gate
  __syncthreads();
  for (int t = tid; t < MT * 128; t += NTHREADS) {
    int q = t >> 7, c = t & 127;
    t1[q * 132 + c] += sigm(P.f2_gate[c]) * t0[q * 260 + c];
  }

  // S14: t0[0:256] = gelu(t1 @ f2_w1 + f2_b1)
  matvec(P.f2_w1, P.f2_b1, t1, 132, t0, 260, 128, 128, 128, 0, 256, wb, 1);
  matvec(P.f2_w1, P.f2_b1, t1, 132, t0, 260, 128, 128, 128, 128, 256, wb, 1);
  // S15: hb = t0 @ f2_w2 + f2_b2
  matvec(P.f2_w2, P.f2_b2, t0, 260, hb, 132, 256, 256, 128, 0, 128, wb, 0);

  // S16: layernorm(hb) with f2_ln
  __syncthreads();
  layernorm16(hb, P.f2_ln_w, P.f2_ln_b);
  __syncthreads();

  // S17: build mi in t0: [h(128), pe(26), coarse(2), 0,0,0,0]
  for (int t = tid; t < MT * 160; t += NTHREADS) {
    int q = t / 160, c = t - q * 160;
    float v;
    if (c < 128) v = hb[q * 132 + c];
    else if (c < 156) v = pec[q * 32 + (c - 128)];
    else v = 0.f;
    t0[q * 260 + c] = v;
  }

  // S18: t1 = gelu(mi @ h_w1 + h_b1)   [156->128]
  matvec(P.h_w1, P.h_b1, t0, 260, t1, 132, 156, 160, 128, 0, 128, wb, 1);
  // S19: t0[0:64] = gelu(t1 @ h_w2 + h_b2)  [128->64]
  matvec(P.h_w2, P.h_b2, t1, 132, t0, 260, 128, 128, 64, 0, 64, wb, 1);

  // S20: delta = t0 @ h_w3 + h_b3; out = coarse + delta
  __syncthreads();
  if (tid < 32) {
    int q = tid >> 1, o = tid & 1;
    float a = P.h_b3[o];
#pragma unroll 8
    for (int k2 = 0; k2 < 64; ++k2) a = fmaf(t0[q * 260 + k2], P.h_w3[k2 * 2 + o], a);
    P.out[(m0 + q) * 2 + o] = pec[q * 32 + 26 + o] + a;
  }
}

extern "C" void kernel_launch(void* const* d_in, const int* in_sizes, int n_in,
                              void* d_out, int out_size, void* d_ws, size_t ws_size,
                              hipStream_t stream) {
  const float* img        = (const float*)d_in[0];
  const float* feat_s8    = (const float*)d_in[1];
  const float* feat_s16   = (const float*)d_in[2];
  const float* coarse_flow= (const float*)d_in[3];
  const float* qc         = (const float*)d_in[4];

  float* ft8  = (float*)d_ws;                      // [2][48][64][128]
  float* ft16 = ft8 + 2 * H8 * W8 * 128;           // [2][24][32][128]

  transpose_cl<<<3072, 256, 0, stream>>>(feat_s8, ft8, 2, 128, H8, W8);
  transpose_cl<<<768, 256, 0, stream>>>(feat_s16, ft16, 2, 128, H16, W16);

  Params P;
  P.img = img; P.feat_s8 = feat_s8; P.feat_s16 = feat_s16;
  P.coarse_flow = coarse_flow; P.qc = qc;
  P.pp_w1 = (const float*)d_in[5];  P.pp_b1 = (const float*)d_in[6];
  P.pp_w2 = (const float*)d_in[7];  P.pp_b2 = (const float*)d_in[8];
  P.p8_w  = (const float*)d_in[9];  P.p8_b  = (const float*)d_in[10];
  P.p16_w = (const float*)d_in[11]; P.p16_b = (const float*)d_in[12];
  P.f1_ph_w = (const float*)d_in[13]; P.f1_ph_b = (const float*)d_in[14];
  P.f1_gate = (const float*)d_in[15];
  P.f1_w1 = (const float*)d_in[16]; P.f1_b1 = (const float*)d_in[17];
  P.f1_w2 = (const float*)d_in[18]; P.f1_b2 = (const float*)d_in[19];
  P.f1_ln_w = (const float*)d_in[20]; P.f1_ln_b = (const float*)d_in[21];
  P.f2_ph_w = (const float*)d_in[22]; P.f2_ph_b = (const float*)d_in[23];
  P.f2_gate = (const float*)d_in[24];
  P.f2_w1 = (const float*)d_in[25]; P.f2_b1 = (const float*)d_in[26];
  P.f2_w2 = (const float*)d_in[27]; P.f2_b2 = (const float*)d_in[28];
  P.f2_ln_w = (const float*)d_in[29]; P.f2_ln_b = (const float*)d_in[30];
  P.h_w1 = (const float*)d_in[31]; P.h_b1 = (const float*)d_in[32];
  P.h_w2 = (const float*)d_in[33]; P.h_b2 = (const float*)d_in[34];
  P.h_w3 = (const float*)d_in[35]; P.h_b3 = (const float*)d_in[36];
  P.ft8 = ft8; P.ft16 = ft16;
  P.out = (float*)d_out;

  ifd_fused<<<MTOT / MT, NTHREADS, 0, stream>>>(P);
}

// Round 2
// 281.677 us; speedup vs baseline: 5.5971x; 5.5971x over previous
//
#include <hip/hip_runtime.h>
#include <math.h>

#define NT 256
#define MB 64            // queries per block
#define MTOT 131072
#define IMG_H 384
#define IMG_W 512
#define H8 48
#define W8 64
#define H16 24
#define W16 32

typedef _Float16 half8_t __attribute__((ext_vector_type(8)));
typedef float f32x4_t __attribute__((ext_vector_type(4)));
typedef unsigned short u16;

// packed weight bases (in halfs) -- fragment order: ((nt*KT + kt)*64 + lane)*8 + j
// element = W[kt*32 + (lane>>4)*8 + j][nt*16 + (lane&15)]  (same k-order as A-side reads)
#define PW_PP1   0
#define PW_PP2   12288
#define PW_P8    28672
#define PW_P16   45056
#define PW_F1PH  61440
#define PW_F1W1  77824
#define PW_F1W2  110592
#define PW_F2PH  143360
#define PW_F2W1  159744
#define PW_F2W2  192512
#define PW_HW1   225280
#define PW_HW2   245760
#define PW_END   253952
#define FT8_OFF  PW_END
#define FT8_CNT  (2*H8*W8*128)
#define FT16_OFF (FT8_OFF + FT8_CNT)

__device__ __forceinline__ u16 tohalf(float v) {
  return __builtin_bit_cast(u16, (_Float16)v);
}
__device__ __forceinline__ float geluf(float x) {
  return 0.5f * x * (1.0f + erff(x * 0.70710678118654752440f));
}

// bilinear on a single [Hd][Wd] f32 plane, align_corners=True + border clamp
__device__ __forceinline__ float bilin_plane(const float* __restrict__ plane,
                                             int Wd, int Hd, float x, float y) {
  x = fminf(fmaxf(x, 0.f), (float)(Wd - 1));
  y = fminf(fmaxf(y, 0.f), (float)(Hd - 1));
  float x0f = floorf(x), y0f = floorf(y);
  int x0 = (int)x0f, y0 = (int)y0f;
  int x1 = min(x0 + 1, Wd - 1), y1 = min(y0 + 1, Hd - 1);
  float wx = x - x0f, wy = y - y0f;
  const float* r0 = plane + y0 * Wd;
  const float* r1 = plane + y1 * Wd;
  float v00 = r0[x0], v01 = r0[x1], v10 = r1[x0], v11 = r1[x1];
  float top = v00 + wx * (v01 - v00);
  float bot = v10 + wx * (v11 - v10);
  return top + wy * (bot - top);
}

// bilinear gather of 8 fp16 channels from channel-last [Hd][Wd][128] fp16
__device__ __forceinline__ void featSample(const u16* __restrict__ ft, int Wd, int Hd,
                                           float x, float y, u16* dstRow, int i16) {
  x = fminf(fmaxf(x, 0.f), (float)(Wd - 1));
  y = fminf(fmaxf(y, 0.f), (float)(Hd - 1));
  float x0f = floorf(x), y0f = floorf(y);
  int x0 = (int)x0f, y0 = (int)y0f;
  int x1 = min(x0 + 1, Wd - 1), y1 = min(y0 + 1, Hd - 1);
  float wx = x - x0f, wy = y - y0f;
  half8_t v00 = *reinterpret_cast<const half8_t*>(ft + (y0 * Wd + x0) * 128 + i16 * 8);
  half8_t v01 = *reinterpret_cast<const half8_t*>(ft + (y0 * Wd + x1) * 128 + i16 * 8);
  half8_t v10 = *reinterpret_cast<const half8_t*>(ft + (y1 * Wd + x0) * 128 + i16 * 8);
  half8_t v11 = *reinterpret_cast<const half8_t*>(ft + (y1 * Wd + x1) * 128 + i16 * 8);
  half8_t r;
#pragma unroll
  for (int j = 0; j < 8; ++j) {
    float top = (float)v00[j] + wx * ((float)v01[j] - (float)v00[j]);
    float bot = (float)v10[j] + wx * ((float)v11[j] - (float)v10[j]);
    r[j] = (_Float16)(top + wy * (bot - top));
  }
  *reinterpret_cast<half8_t*>(dstRow + i16 * 8) = r;
}

// 64-row x NTOT-col matvec via MFMA 16x16x32 fp16.
// A rows from LDS (fp16, k-steps < splitKT from aA/strA, rest from aB/strB).
// B fragments from packed global weights. Waves split N (nt = wave + 4*i).
// Out: fp16 to oA (nt < oSplitNt) or oB. Bias f32, optional exact gelu.
template <int NTW>
__device__ __forceinline__ void mmv(
    const u16* __restrict__ wpk, int KT,
    const u16* aA, int strA, const u16* aB, int strB, int splitKT,
    const float* __restrict__ bias, int act,
    u16* oA, int ostrA, u16* oB, int ostrB, int oSplitNt) {
  const int tid = threadIdx.x;
  const int lane = tid & 63;
  const int w = tid >> 6;
  const int l15 = lane & 15;
  const int g = lane >> 4;
  f32x4_t acc[NTW][4];
#pragma unroll
  for (int i = 0; i < NTW; ++i)
#pragma unroll
    for (int mt = 0; mt < 4; ++mt) acc[i][mt] = (f32x4_t){0.f, 0.f, 0.f, 0.f};
  for (int kt = 0; kt < KT; ++kt) {
    const u16* ab; int str;
    if (kt < splitKT) { ab = aA + kt * 32; str = strA; }
    else             { ab = aB + (kt - splitKT) * 32; str = strB; }
    half8_t af[4];
#pragma unroll
    for (int mt = 0; mt < 4; ++mt)
      af[mt] = *reinterpret_cast<const half8_t*>(ab + (mt * 16 + l15) * str + g * 8);
#pragma unroll
    for (int i = 0; i < NTW; ++i) {
      int nt = w + (i << 2);
      half8_t bf = *reinterpret_cast<const half8_t*>(wpk + ((nt * KT + kt) * 64 + lane) * 8);
#pragma unroll
      for (int mt = 0; mt < 4; ++mt)
        acc[i][mt] = __builtin_amdgcn_mfma_f32_16x16x32_f16(af[mt], bf, acc[i][mt], 0, 0, 0);
    }
  }
#pragma unroll
  for (int i = 0; i < NTW; ++i) {
    int nt = w + (i << 2);
    int colg = (nt << 4) + l15;
    float bv = bias[colg];
    u16* ob; int colB, ostr;
    if (nt < oSplitNt) { ob = oA; colB = colg; ostr = ostrA; }
    else { ob = oB; colB = colg - (oSplitNt << 4); ostr = ostrB; }
#pragma unroll
    for (int mt = 0; mt < 4; ++mt) {
#pragma unroll
      for (int r = 0; r < 4; ++r) {
        float v = acc[i][mt][r] + bv;
        if (act) v = geluf(v);
        int row = (mt << 4) + (g << 2) + r;
        ob[row * ostr + colB] = tohalf(v);
      }
    }
  }
}

// layernorm rows of ab1 [64][136] -> hb [64][168] cols 0..127
__device__ __forceinline__ void lnorm(const u16* src, u16* dst,
                                      const float* __restrict__ lw,
                                      const float* __restrict__ lb) {
  const int tid = threadIdx.x;
  int q = tid >> 2, s = tid & 3;
  const u16* rp = src + q * 136 + s * 32;
  float xs[32];
  float sum = 0.f, sum2 = 0.f;
#pragma unroll
  for (int c8 = 0; c8 < 4; ++c8) {
    half8_t v = *reinterpret_cast<const half8_t*>(rp + c8 * 8);
#pragma unroll
    for (int j = 0; j < 8; ++j) {
      float x = (float)v[j];
      xs[c8 * 8 + j] = x; sum += x; sum2 += x * x;
    }
  }
  sum += __shfl_xor(sum, 1); sum2 += __shfl_xor(sum2, 1);
  sum += __shfl_xor(sum, 2); sum2 += __shfl_xor(sum2, 2);
  float mean = sum * 0.0078125f;
  float var = sum2 * 0.0078125f - mean * mean;
  float rstd = rsqrtf(var + 1e-5f);
  u16* op = dst + q * 168 + s * 32;
#pragma unroll
  for (int c8 = 0; c8 < 4; ++c8) {
    half8_t r;
#pragma unroll
    for (int j = 0; j < 8; ++j) {
      int c = s * 32 + c8 * 8 + j;
      r[j] = (_Float16)((xs[c8 * 8 + j] - mean) * rstd * lw[c] + lb[c]);
    }
    *reinterpret_cast<half8_t*>(op + c8 * 8) = r;
  }
}

// ---------------- prep kernels ----------------
struct PackArgs { const float* src[12]; u16* dst; };

__global__ void pack_weights(PackArgs a) {
  const int KTs[12]   = {3, 4, 4, 4, 4, 4, 8, 4, 4, 8, 5, 4};
  const int Ks[12]    = {75, 128, 128, 128, 128, 128, 256, 128, 128, 256, 156, 128};
  const int Ns[12]    = {128, 128, 128, 128, 128, 256, 128, 128, 256, 128, 128, 64};
  const int bases[13] = {0, 12288, 28672, 45056, 61440, 77824, 110592, 143360,
                         159744, 192512, 225280, 245760, 253952};
  int stride = gridDim.x * blockDim.x;
  for (int i = blockIdx.x * blockDim.x + threadIdx.x; i < PW_END; i += stride) {
    int s = 0;
    while (i >= bases[s + 1]) ++s;
    int rem = i - bases[s];
    int e = rem & 511, lane = e >> 3, j = e & 7;
    int ntkt = rem >> 9;
    int kt = ntkt % KTs[s], nt = ntkt / KTs[s];
    int k = kt * 32 + ((lane >> 4) << 3) + j;
    int col = (nt << 4) + (lane & 15);
    float v = (k < Ks[s]) ? a.src[s][k * Ns[s] + col] : 0.f;
    a.dst[i] = tohalf(v);
  }
}

__global__ void cvt_cl_f16(const float* __restrict__ src, u16* __restrict__ dst,
                           int Hd, int Wd) {
  int total = 2 * 128 * Hd * Wd;
  int stride = gridDim.x * blockDim.x;
  for (int i = blockIdx.x * blockDim.x + threadIdx.x; i < total; i += stride) {
    int x = i % Wd;
    int t = i / Wd;
    int y = t % Hd; t /= Hd;
    int c = t % 128;
    int b = t / 128;
    dst[((b * Hd + y) * Wd + x) * 128 + c] = tohalf(src[i]);
  }
}

// ---------------- main fused kernel ----------------
struct KParams {
  const float *img, *coarse_flow, *qc;
  const u16 *wpk, *ft8, *ft16;
  const float *pp_b1, *pp_b2, *p8_b, *p16_b;
  const float *f1_ph_b, *f1_gate, *f1_b1, *f1_b2, *f1_ln_w, *f1_ln_b;
  const float *f2_ph_b, *f2_gate, *f2_b1, *f2_b2, *f2_ln_w, *f2_ln_b;
  const float *h_b1, *h_b2, *h_w3, *h_b3;
  float* out;
};

__global__ __launch_bounds__(NT, 2) void ifd_mfma(KParams P) {
  __shared__ __align__(16) u16 smem[28160];   // ab0[64][136] ab1[64][136] hb[64][168]
  __shared__ float qcL[128];
  __shared__ float cb[128];
  __shared__ float sgate[128];
  u16* ab0 = smem;
  u16* ab1 = smem + 8704;
  u16* hb  = smem + 17408;

  const int tid = threadIdx.x;
  const int m0 = blockIdx.x * MB;

  // P0a: query coords to LDS
  if (tid < 128) qcL[tid] = P.qc[m0 * 2 + tid];
  __syncthreads();

  // P0b: patches -> ab0 cols 0..95; pe/coarse -> hb cols 128..167 + cb
  for (int i = tid; i < MB * 96; i += NT) {
    int q = i / 96, c = i - q * 96;
    u16 val = 0;
    if (c < 75) {
      int m = m0 + q, b = m >> 16;
      float qx = qcL[2 * q], qy = qcL[2 * q + 1];
      int p = c / 3, ch = c - p * 3;
      int iy = p / 5, ix = p - iy * 5;
      const float* plane = P.img + (b * 3 + ch) * (IMG_H * IMG_W);
      val = tohalf(bilin_plane(plane, IMG_W, IMG_H,
                               qx + (float)(ix - 2), qy + (float)(iy - 2)));
    }
    ab0[q * 136 + c] = val;
  }
  for (int i = tid; i < MB * 40; i += NT) {
    int q = i / 40, c = i - q * 40;
    int m = m0 + q, b = m >> 16;
    float qx = qcL[2 * q], qy = qcL[2 * q + 1];
    float val = 0.f;
    if (c < 26) {
      float qx8 = qx * 0.125f, qy8 = qy * 0.125f;
      float lx = (qx8 - rintf(qx8)) * 2.f, ly = (qy8 - rintf(qy8)) * 2.f;
      if (c < 2) val = c ? ly : lx;
      else {
        int k = c - 2;
        int dim = k / 12, tt = k - dim * 12;
        int band = tt % 6, iscos = tt / 6;
        float loc = dim ? ly : lx;
        float ang = loc * 3.14159265358979323846f * (float)(1 << band);
        val = iscos ? cosf(ang) : sinf(ang);
      }
    } else if (c < 28) {
      int o = c - 26;
      float x8 = qx * (63.f / 511.f), y8 = qy * (47.f / 383.f);
      float cv = 8.f * bilin_plane(P.coarse_flow + (b * 2 + o) * (H8 * W8), W8, H8, x8, y8);
      cb[q * 2 + o] = cv;
      val = cv;
    }
    hb[q * 168 + 128 + c] = tohalf(val);
  }
  __syncthreads();

  // S1: ab1 = gelu(patches @ pp_w1 + pp_b1)   K=96(75)
  mmv<2>(P.wpk + PW_PP1, 3, ab0, 136, ab0, 136, 3, P.pp_b1, 1, ab1, 136, ab1, 136, 16);
  __syncthreads();
  // S2: hb(h) = ab1 @ pp_w2 + pp_b2 ; also sample f8 -> ab0
  mmv<2>(P.wpk + PW_PP2, 4, ab1, 136, ab1, 136, 4, P.pp_b2, 0, hb, 168, hb, 168, 16);
  for (int i = tid; i < MB * 16; i += NT) {
    int q = i >> 4, i16 = i & 15;
    int m = m0 + q, b = m >> 16;
    float x = qcL[2 * q] * (63.f / 511.f), y = qcL[2 * q + 1] * (47.f / 383.f);
    featSample(P.ft8 + b * (H8 * W8 * 128), W8, H8, x, y, ab0 + q * 136, i16);
  }
  __syncthreads();
  // S4: ab1 = f8 @ p8_w + p8_b
  mmv<2>(P.wpk + PW_P8, 4, ab0, 136, ab0, 136, 4, P.p8_b, 0, ab1, 136, ab1, 136, 16);
  __syncthreads();
  // S5: ab0 = h @ f1_ph_w + f1_ph_b ; sgate = sigmoid(f1_gate)
  mmv<2>(P.wpk + PW_F1PH, 4, hb, 168, hb, 168, 4, P.f1_ph_b, 0, ab0, 136, ab0, 136, 16);
  if (tid < 128) sgate[tid] = 1.f / (1.f + expf(-P.f1_gate[tid]));
  __syncthreads();
  // F1: ab1 += sgate * ab0
  for (int i = tid; i < MB * 16; i += NT) {
    int q = i >> 4, cg = i & 15;
    half8_t aV = *reinterpret_cast<const half8_t*>(ab1 + q * 136 + cg * 8);
    half8_t dV = *reinterpret_cast<const half8_t*>(ab0 + q * 136 + cg * 8);
    half8_t r;
#pragma unroll
    for (int j = 0; j < 8; ++j)
      r[j] = (_Float16)((float)aV[j] + sgate[cg * 8 + j] * (float)dV[j]);
    *reinterpret_cast<half8_t*>(ab1 + q * 136 + cg * 8) = r;
  }
  __syncthreads();
  // S7: wide = gelu(ab1 @ f1_w1 + f1_b1), cols 0-127 -> ab0, 128-255 -> hb
  mmv<4>(P.wpk + PW_F1W1, 4, ab1, 136, ab1, 136, 4, P.f1_b1, 1, ab0, 136, hb, 168, 8);
  __syncthreads();
  // S8: ab1 = wide @ f1_w2 + f1_b2  (K=256)
  mmv<2>(P.wpk + PW_F1W2, 8, ab0, 136, hb, 168, 4, P.f1_b2, 0, ab1, 136, ab1, 136, 16);
  __syncthreads();
  // LN1 -> hb
  lnorm(ab1, hb, P.f1_ln_w, P.f1_ln_b);
  __syncthreads();
  // S10: sample f16 -> ab0
  for (int i = tid; i < MB * 16; i += NT) {
    int q = i >> 4, i16 = i & 15;
    int m = m0 + q, b = m >> 16;
    float x = qcL[2 * q] * (31.f / 511.f), y = qcL[2 * q + 1] * (23.f / 383.f);
    featSample(P.ft16 + b * (H16 * W16 * 128), W16, H16, x, y, ab0 + q * 136, i16);
  }
  __syncthreads();
  // S11: ab1 = f16 @ p16_w + p16_b
  mmv<2>(P.wpk + PW_P16, 4, ab0, 136, ab0, 136, 4, P.p16_b, 0, ab1, 136, ab1, 136, 16);
  __syncthreads();
  // S12: ab0 = h @ f2_ph_w + f2_ph_b ; sgate2
  mmv<2>(P.wpk + PW_F2PH, 4, hb, 168, hb, 168, 4, P.f2_ph_b, 0, ab0, 136, ab0, 136, 16);
  if (tid < 128) sgate[tid] = 1.f / (1.f + expf(-P.f2_gate[tid]));
  __syncthreads();
  // F2
  for (int i = tid; i < MB * 16; i += NT) {
    int q = i >> 4, cg = i & 15;
    half8_t aV = *reinterpret_cast<const half8_t*>(ab1 + q * 136 + cg * 8);
    half8_t dV = *reinterpret_cast<const half8_t*>(ab0 + q * 136 + cg * 8);
    half8_t r;
#pragma unroll
    for (int j = 0; j < 8; ++j)
      r[j] = (_Float16)((float)aV[j] + sgate[cg * 8 + j] * (float)dV[j]);
    *reinterpret_cast<half8_t*>(ab1 + q * 136 + cg * 8) = r;
  }
  __syncthreads();
  // S14: wide2
  mmv<4>(P.wpk + PW_F2W1, 4, ab1, 136, ab1, 136, 4, P.f2_b1, 1, ab0, 136, hb, 168, 8);
  __syncthreads();
  // S15
  mmv<2>(P.wpk + PW_F2W2, 8, ab0, 136, hb, 168, 4, P.f2_b2, 0, ab1, 136, ab1, 136, 16);
  __syncthreads();
  // LN2 -> hb
  lnorm(ab1, hb, P.f2_ln_w, P.f2_ln_b);
  __syncthreads();
  // S18: ab1 = gelu(mi @ h_w1 + h_b1)  (K=160: hb cols 0..159 = h|pe|coarse|0)
  mmv<2>(P.wpk + PW_HW1, 5, hb, 168, hb, 168, 5, P.h_b1, 1, ab1, 136, ab1, 136, 16);
  __syncthreads();
  // S19: ab0 cols0-63 = gelu(ab1 @ h_w2 + h_b2)
  mmv<1>(P.wpk + PW_HW2, 4, ab1, 136, ab1, 136, 4, P.h_b2, 1, ab0, 136, ab0, 136, 16);
  __syncthreads();
  // S20: out = coarse + (g @ h_w3 + h_b3)
  if (tid < 128) {
    int q = tid >> 1, o = tid & 1;
    float acc = P.h_b3[o];
    const u16* rp = ab0 + q * 136;
#pragma unroll
    for (int c8 = 0; c8 < 8; ++c8) {
      half8_t v = *reinterpret_cast<const half8_t*>(rp + c8 * 8);
#pragma unroll
      for (int j = 0; j < 8; ++j) acc += (float)v[j] * P.h_w3[(c8 * 8 + j) * 2 + o];
    }
    P.out[(m0 + q) * 2 + o] = cb[q * 2 + o] + acc;
  }
}

extern "C" void kernel_launch(void* const* d_in, const int* in_sizes, int n_in,
                              void* d_out, int out_size, void* d_ws, size_t ws_size,
                              hipStream_t stream) {
  u16* wp = (u16*)d_ws;

  PackArgs pa;
  pa.src[0]  = (const float*)d_in[5];   // pp_w1
  pa.src[1]  = (const float*)d_in[7];   // pp_w2
  pa.src[2]  = (const float*)d_in[9];   // p8_w
  pa.src[3]  = (const float*)d_in[11];  // p16_w
  pa.src[4]  = (const float*)d_in[13];  // f1_ph_w
  pa.src[5]  = (const float*)d_in[16];  // f1_w1
  pa.src[6]  = (const float*)d_in[18];  // f1_w2
  pa.src[7]  = (const float*)d_in[22];  // f2_ph_w
  pa.src[8]  = (const float*)d_in[25];  // f2_w1
  pa.src[9]  = (const float*)d_in[27];  // f2_w2
  pa.src[10] = (const float*)d_in[31];  // h_w1
  pa.src[11] = (const float*)d_in[33];  // h_w2
  pa.dst = wp;
  pack_weights<<<512, 256, 0, stream>>>(pa);
  cvt_cl_f16<<<1024, 256, 0, stream>>>((const float*)d_in[1], wp + FT8_OFF, H8, W8);
  cvt_cl_f16<<<256, 256, 0, stream>>>((const float*)d_in[2], wp + FT16_OFF, H16, W16);

  KParams P;
  P.img = (const float*)d_in[0];
  P.coarse_flow = (const float*)d_in[3];
  P.qc = (const float*)d_in[4];
  P.wpk = wp; P.ft8 = wp + FT8_OFF; P.ft16 = wp + FT16_OFF;
  P.pp_b1 = (const float*)d_in[6];  P.pp_b2 = (const float*)d_in[8];
  P.p8_b = (const float*)d_in[10];  P.p16_b = (const float*)d_in[12];
  P.f1_ph_b = (const float*)d_in[14]; P.f1_gate = (const float*)d_in[15];
  P.f1_b1 = (const float*)d_in[17]; P.f1_b2 = (const float*)d_in[19];
  P.f1_ln_w = (const float*)d_in[20]; P.f1_ln_b = (const float*)d_in[21];
  P.f2_ph_b = (const float*)d_in[23]; P.f2_gate = (const float*)d_in[24];
  P.f2_b1 = (const float*)d_in[26]; P.f2_b2 = (const float*)d_in[28];
  P.f2_ln_w = (const float*)d_in[29]; P.f2_ln_b = (const float*)d_in[30];
  P.h_b1 = (const float*)d_in[32]; P.h_b2 = (const float*)d_in[34];
  P.h_w3 = (const float*)d_in[35]; P.h_b3 = (const float*)d_in[36];
  P.out = (float*)d_out;

  ifd_mfma<<<MTOT / MB, NT, 0, stream>>>(P);
}

// Round 3
// 205.119 us; speedup vs baseline: 7.6862x; 1.3732x over previous
//
#include <hip/hip_runtime.h>
#include <math.h>

#define NT 256
#define MB 32            // queries per block
#define MTOT 131072
#define IMG_H 384
#define IMG_W 512
#define H8 48
#define W8 64
#define H16 24
#define W16 32

typedef _Float16 half8_t __attribute__((ext_vector_type(8)));
typedef float f32x4_t __attribute__((ext_vector_type(4)));
typedef unsigned short u16;

// packed weight bases (in halfs) -- fragment order: ((nt*KT + kt)*64 + lane)*8 + j
// element = W[kt*32 + (lane>>4)*8 + j][nt*16 + (lane&15)]  (same k-order as A-side reads)
#define PW_PP1   0
#define PW_PP2   12288
#define PW_P8    28672
#define PW_P16   45056
#define PW_F1PH  61440
#define PW_F1W1  77824
#define PW_F1W2  110592
#define PW_F2PH  143360
#define PW_F2W1  159744
#define PW_F2W2  192512
#define PW_HW1   225280
#define PW_HW2   245760
#define PW_END   253952
#define FT8_OFF  PW_END
#define FT8_CNT  (2*H8*W8*128)
#define FT16_OFF (FT8_OFF + FT8_CNT)

__device__ __forceinline__ u16 tohalf(float v) {
  return __builtin_bit_cast(u16, (_Float16)v);
}
// tanh-form gelu: x * sigmoid(1.5957691x + 0.07135482x^3); |err vs exact erf-gelu| < 3e-3
__device__ __forceinline__ float geluf(float x) {
  float x2 = x * x;
  float t = x * fmaf(x2, 0.0713548162726f, 1.5957691216057308f);
  float e = __expf(-t);
  return x * __builtin_amdgcn_rcpf(1.0f + e);
}
__device__ __forceinline__ float sigm(float x) {
  return __builtin_amdgcn_rcpf(1.0f + __expf(-x));
}

// bilinear on a single [Hd][Wd] f32 plane, align_corners=True + border clamp
__device__ __forceinline__ float bilin_plane(const float* __restrict__ plane,
                                             int Wd, int Hd, float x, float y) {
  x = fminf(fmaxf(x, 0.f), (float)(Wd - 1));
  y = fminf(fmaxf(y, 0.f), (float)(Hd - 1));
  float x0f = floorf(x), y0f = floorf(y);
  int x0 = (int)x0f, y0 = (int)y0f;
  int x1 = min(x0 + 1, Wd - 1), y1 = min(y0 + 1, Hd - 1);
  float wx = x - x0f, wy = y - y0f;
  const float* r0 = plane + y0 * Wd;
  const float* r1 = plane + y1 * Wd;
  float v00 = r0[x0], v01 = r0[x1], v10 = r1[x0], v11 = r1[x1];
  float top = v00 + wx * (v01 - v00);
  float bot = v10 + wx * (v11 - v10);
  return top + wy * (bot - top);
}

// bilinear gather of 8 fp16 channels from channel-last [Hd][Wd][128] fp16
__device__ __forceinline__ void featSample(const u16* __restrict__ ft, int Wd, int Hd,
                                           float x, float y, u16* dstRow, int i16) {
  x = fminf(fmaxf(x, 0.f), (float)(Wd - 1));
  y = fminf(fmaxf(y, 0.f), (float)(Hd - 1));
  float x0f = floorf(x), y0f = floorf(y);
  int x0 = (int)x0f, y0 = (int)y0f;
  int x1 = min(x0 + 1, Wd - 1), y1 = min(y0 + 1, Hd - 1);
  float wx = x - x0f, wy = y - y0f;
  half8_t v00 = *reinterpret_cast<const half8_t*>(ft + (y0 * Wd + x0) * 128 + i16 * 8);
  half8_t v01 = *reinterpret_cast<const half8_t*>(ft + (y0 * Wd + x1) * 128 + i16 * 8);
  half8_t v10 = *reinterpret_cast<const half8_t*>(ft + (y1 * Wd + x0) * 128 + i16 * 8);
  half8_t v11 = *reinterpret_cast<const half8_t*>(ft + (y1 * Wd + x1) * 128 + i16 * 8);
  half8_t r;
#pragma unroll
  for (int j = 0; j < 8; ++j) {
    float top = (float)v00[j] + wx * ((float)v01[j] - (float)v00[j]);
    float bot = (float)v10[j] + wx * ((float)v11[j] - (float)v10[j]);
    r[j] = (_Float16)(top + wy * (bot - top));
  }
  *reinterpret_cast<half8_t*>(dstRow + i16 * 8) = r;
}

// 32-row x (NTW*4*16)-col matvec via MFMA 16x16x32 fp16, 4 waves split N.
// ACT: 0=none, 1=gelu, 2=gated add (dst += sigmoid(gate[col]) * (acc+bias))
template <int NTW, int KT, int SPLITKT, int ACT>
__device__ __forceinline__ void mmv(
    const u16* __restrict__ wpk,
    const u16* aA, int strA, const u16* aB, int strB,
    const float* __restrict__ bias, const float* __restrict__ gate,
    u16* oA, int ostrA, u16* oB, int ostrB, int oSplitNt) {
  const int tid = threadIdx.x;
  const int lane = tid & 63;
  const int w = tid >> 6;
  const int l15 = lane & 15;
  const int g = lane >> 4;
  f32x4_t acc[NTW][2];
#pragma unroll
  for (int i = 0; i < NTW; ++i) {
    acc[i][0] = (f32x4_t){0.f, 0.f, 0.f, 0.f};
    acc[i][1] = (f32x4_t){0.f, 0.f, 0.f, 0.f};
  }
#pragma unroll
  for (int kt = 0; kt < KT; ++kt) {
    const u16* ab = (kt < SPLITKT) ? (aA + kt * 32) : (aB + (kt - SPLITKT) * 32);
    const int str = (kt < SPLITKT) ? strA : strB;
    half8_t af0 = *reinterpret_cast<const half8_t*>(ab + l15 * str + g * 8);
    half8_t af1 = *reinterpret_cast<const half8_t*>(ab + (16 + l15) * str + g * 8);
#pragma unroll
    for (int i = 0; i < NTW; ++i) {
      const int nt = w + (i << 2);
      half8_t bf = *reinterpret_cast<const half8_t*>(wpk + ((nt * KT + kt) * 64 + lane) * 8);
      acc[i][0] = __builtin_amdgcn_mfma_f32_16x16x32_f16(af0, bf, acc[i][0], 0, 0, 0);
      acc[i][1] = __builtin_amdgcn_mfma_f32_16x16x32_f16(af1, bf, acc[i][1], 0, 0, 0);
    }
  }
#pragma unroll
  for (int i = 0; i < NTW; ++i) {
    const int nt = w + (i << 2);
    const int colg = (nt << 4) + l15;
    float bv = bias[colg];
    float sg = 0.f;
    if (ACT == 2) sg = sigm(gate[colg]);
    u16* ob; int colB, ostr;
    if (nt < oSplitNt) { ob = oA; colB = colg; ostr = ostrA; }
    else { ob = oB; colB = colg - (oSplitNt << 4); ostr = ostrB; }
#pragma unroll
    for (int mt = 0; mt < 2; ++mt) {
#pragma unroll
      for (int r = 0; r < 4; ++r) {
        const int row = (mt << 4) + (g << 2) + r;
        float v = acc[i][mt][r] + bv;
        if (ACT == 1) v = geluf(v);
        if (ACT == 2) {
          _Float16 old = __builtin_bit_cast(_Float16, ob[row * ostr + colB]);
          v = (float)old + sg * v;
        }
        ob[row * ostr + colB] = tohalf(v);
      }
    }
  }
}

// layernorm rows of src [32][136] -> dst [32][168] cols 0..127 (8 threads/row)
__device__ __forceinline__ void lnorm(const u16* src, u16* dst,
                                      const float* __restrict__ lw,
                                      const float* __restrict__ lb) {
  const int tid = threadIdx.x;
  int q = tid >> 3, s = tid & 7;
  const u16* rp = src + q * 136 + s * 16;
  float xs[16];
  float sum = 0.f, sum2 = 0.f;
#pragma unroll
  for (int c8 = 0; c8 < 2; ++c8) {
    half8_t v = *reinterpret_cast<const half8_t*>(rp + c8 * 8);
#pragma unroll
    for (int j = 0; j < 8; ++j) {
      float x = (float)v[j];
      xs[c8 * 8 + j] = x; sum += x; sum2 += x * x;
    }
  }
  sum += __shfl_xor(sum, 1); sum2 += __shfl_xor(sum2, 1);
  sum += __shfl_xor(sum, 2); sum2 += __shfl_xor(sum2, 2);
  sum += __shfl_xor(sum, 4); sum2 += __shfl_xor(sum2, 4);
  float mean = sum * 0.0078125f;
  float var = sum2 * 0.0078125f - mean * mean;
  float rstd = rsqrtf(var + 1e-5f);
  u16* op = dst + q * 168 + s * 16;
#pragma unroll
  for (int c8 = 0; c8 < 2; ++c8) {
    half8_t r;
#pragma unroll
    for (int j = 0; j < 8; ++j) {
      int c = s * 16 + c8 * 8 + j;
      r[j] = (_Float16)((xs[c8 * 8 + j] - mean) * rstd * lw[c] + lb[c]);
    }
    *reinterpret_cast<half8_t*>(op + c8 * 8) = r;
  }
}

// ---------------- prep kernels ----------------
struct PackArgs { const float* src[12]; u16* dst; };

__global__ void pack_weights(PackArgs a) {
  const int KTs[12]   = {3, 4, 4, 4, 4, 4, 8, 4, 4, 8, 5, 4};
  const int Ks[12]    = {75, 128, 128, 128, 128, 128, 256, 128, 128, 256, 156, 128};
  const int Ns[12]    = {128, 128, 128, 128, 128, 256, 128, 128, 256, 128, 128, 64};
  const int bases[13] = {0, 12288, 28672, 45056, 61440, 77824, 110592, 143360,
                         159744, 192512, 225280, 245760, 253952};
  int stride = gridDim.x * blockDim.x;
  for (int i = blockIdx.x * blockDim.x + threadIdx.x; i < PW_END; i += stride) {
    int s = 0;
    while (i >= bases[s + 1]) ++s;
    int rem = i - bases[s];
    int e = rem & 511, lane = e >> 3, j = e & 7;
    int ntkt = rem >> 9;
    int kt = ntkt % KTs[s], nt = ntkt / KTs[s];
    int k = kt * 32 + ((lane >> 4) << 3) + j;
    int col = (nt << 4) + (lane & 15);
    float v = (k < Ks[s]) ? a.src[s][k * Ns[s] + col] : 0.f;
    a.dst[i] = tohalf(v);
  }
}

__global__ void cvt_cl_f16(const float* __restrict__ src, u16* __restrict__ dst,
                           int Hd, int Wd) {
  int total = 2 * 128 * Hd * Wd;
  int stride = gridDim.x * blockDim.x;
  for (int i = blockIdx.x * blockDim.x + threadIdx.x; i < total; i += stride) {
    int x = i % Wd;
    int t = i / Wd;
    int y = t % Hd; t /= Hd;
    int c = t % 128;
    int b = t / 128;
    dst[((b * Hd + y) * Wd + x) * 128 + c] = tohalf(src[i]);
  }
}

// ---------------- main fused kernel ----------------
struct KParams {
  const float *img, *coarse_flow, *qc;
  const u16 *wpk, *ft8, *ft16;
  const float *pp_b1, *pp_b2, *p8_b, *p16_b;
  const float *f1_ph_b, *f1_gate, *f1_b1, *f1_b2, *f1_ln_w, *f1_ln_b;
  const float *f2_ph_b, *f2_gate, *f2_b1, *f2_b2, *f2_ln_w, *f2_ln_b;
  const float *h_b1, *h_b2, *h_w3, *h_b3;
  float* out;
};

__global__ __launch_bounds__(NT, 4) void ifd_mfma(KParams P) {
  __shared__ __align__(16) u16 smem[14080];  // ab0[32][136] ab1[32][136] hb[32][168]
  __shared__ float qcL[64];
  __shared__ float cb[64];
  u16* ab0 = smem;
  u16* ab1 = smem + 4352;
  u16* hb  = smem + 8704;

  const int tid = threadIdx.x;
  const int m0 = blockIdx.x * MB;

  // P0a: query coords to LDS
  if (tid < 64) qcL[tid] = P.qc[m0 * 2 + tid];
  __syncthreads();

  // P0b: patches -> ab0 cols 0..95; pe/coarse -> hb cols 128..167 + cb
  for (int i = tid; i < MB * 96; i += NT) {
    int q = i / 96, c = i - q * 96;
    u16 val = 0;
    if (c < 75) {
      int m = m0 + q, b = m >> 16;
      float qx = qcL[2 * q], qy = qcL[2 * q + 1];
      int p = c / 3, ch = c - p * 3;
      int iy = p / 5, ix = p - iy * 5;
      const float* plane = P.img + (b * 3 + ch) * (IMG_H * IMG_W);
      val = tohalf(bilin_plane(plane, IMG_W, IMG_H,
                               qx + (float)(ix - 2), qy + (float)(iy - 2)));
    }
    ab0[q * 136 + c] = val;
  }
  for (int i = tid; i < MB * 40; i += NT) {
    int q = i / 40, c = i - q * 40;
    int m = m0 + q, b = m >> 16;
    float qx = qcL[2 * q], qy = qcL[2 * q + 1];
    float val = 0.f;
    if (c < 26) {
      float qx8 = qx * 0.125f, qy8 = qy * 0.125f;
      float lx = (qx8 - rintf(qx8)) * 2.f, ly = (qy8 - rintf(qy8)) * 2.f;
      if (c < 2) val = c ? ly : lx;
      else {
        int k = c - 2;
        int dim = k / 12, tt = k - dim * 12;
        int band = tt % 6, iscos = tt / 6;
        float loc = dim ? ly : lx;
        float ang = loc * 3.14159265358979323846f * (float)(1 << band);
        val = iscos ? __cosf(ang) : __sinf(ang);
      }
    } else if (c < 28) {
      int o = c - 26;
      float x8 = qx * (63.f / 511.f), y8 = qy * (47.f / 383.f);
      float cv = 8.f * bilin_plane(P.coarse_flow + (b * 2 + o) * (H8 * W8), W8, H8, x8, y8);
      cb[q * 2 + o] = cv;
      val = cv;
    }
    hb[q * 168 + 128 + c] = tohalf(val);
  }
  __syncthreads();

  // S1: ab1 = gelu(patches @ pp_w1 + pp_b1)
  mmv<2, 3, 3, 1>(P.wpk + PW_PP1, ab0, 136, ab0, 136, P.pp_b1, nullptr,
                  ab1, 136, ab1, 136, 16);
  __syncthreads();
  // S2: hb(h) = ab1 @ pp_w2 + pp_b2 ; sample f8 -> ab0
  mmv<2, 4, 4, 0>(P.wpk + PW_PP2, ab1, 136, ab1, 136, P.pp_b2, nullptr,
                  hb, 168, hb, 168, 16);
  for (int i = tid; i < MB * 16; i += NT) {
    int q = i >> 4, i16 = i & 15;
    int m = m0 + q, b = m >> 16;
    float x = qcL[2 * q] * (63.f / 511.f), y = qcL[2 * q + 1] * (47.f / 383.f);
    featSample(P.ft8 + b * (H8 * W8 * 128), W8, H8, x, y, ab0 + q * 136, i16);
  }
  __syncthreads();
  // S4: ab1 = f8 @ p8_w + p8_b
  mmv<2, 4, 4, 0>(P.wpk + PW_P8, ab0, 136, ab0, 136, P.p8_b, nullptr,
                  ab1, 136, ab1, 136, 16);
  __syncthreads();
  // S5: ab1 += sigmoid(f1_gate) * (h @ f1_ph_w + f1_ph_b)
  mmv<2, 4, 4, 2>(P.wpk + PW_F1PH, hb, 168, hb, 168, P.f1_ph_b, P.f1_gate,
                  ab1, 136, ab1, 136, 16);
  __syncthreads();
  // S7: wide = gelu(ab1 @ f1_w1 + f1_b1): cols 0-127 -> ab0, 128-255 -> hb(0..127)
  mmv<4, 4, 4, 1>(P.wpk + PW_F1W1, ab1, 136, ab1, 136, P.f1_b1, nullptr,
                  ab0, 136, hb, 168, 8);
  __syncthreads();
  // S8: ab1 = wide @ f1_w2 + f1_b2 (K=256)
  mmv<2, 8, 4, 0>(P.wpk + PW_F1W2, ab0, 136, hb, 168, P.f1_b2, nullptr,
                  ab1, 136, ab1, 136, 16);
  __syncthreads();
  // LN1 -> hb ; sample f16 -> ab0 (independent buffers)
  lnorm(ab1, hb, P.f1_ln_w, P.f1_ln_b);
  for (int i = tid; i < MB * 16; i += NT) {
    int q = i >> 4, i16 = i & 15;
    int m = m0 + q, b = m >> 16;
    float x = qcL[2 * q] * (31.f / 511.f), y = qcL[2 * q + 1] * (23.f / 383.f);
    featSample(P.ft16 + b * (H16 * W16 * 128), W16, H16, x, y, ab0 + q * 136, i16);
  }
  __syncthreads();
  // S11: ab1 = f16 @ p16_w + p16_b
  mmv<2, 4, 4, 0>(P.wpk + PW_P16, ab0, 136, ab0, 136, P.p16_b, nullptr,
                  ab1, 136, ab1, 136, 16);
  __syncthreads();
  // S12: ab1 += sigmoid(f2_gate) * (h @ f2_ph_w + f2_ph_b)
  mmv<2, 4, 4, 2>(P.wpk + PW_F2PH, hb, 168, hb, 168, P.f2_ph_b, P.f2_gate,
                  ab1, 136, ab1, 136, 16);
  __syncthreads();
  // S14: wide2
  mmv<4, 4, 4, 1>(P.wpk + PW_F2W1, ab1, 136, ab1, 136, P.f2_b1, nullptr,
                  ab0, 136, hb, 168, 8);
  __syncthreads();
  // S15: ab1 = wide2 @ f2_w2 + f2_b2
  mmv<2, 8, 4, 0>(P.wpk + PW_F2W2, ab0, 136, hb, 168, P.f2_b2, nullptr,
                  ab1, 136, ab1, 136, 16);
  __syncthreads();
  // LN2 -> hb
  lnorm(ab1, hb, P.f2_ln_w, P.f2_ln_b);
  __syncthreads();
  // S18: ab1 = gelu(mi @ h_w1 + h_b1)  (K=160: hb = h | pe | coarse | 0)
  mmv<2, 5, 5, 1>(P.wpk + PW_HW1, hb, 168, hb, 168, P.h_b1, nullptr,
                  ab1, 136, ab1, 136, 16);
  __syncthreads();
  // S19: ab0 cols 0..63 = gelu(ab1 @ h_w2 + h_b2)
  mmv<1, 4, 4, 1>(P.wpk + PW_HW2, ab1, 136, ab1, 136, P.h_b2, nullptr,
                  ab0, 136, ab0, 136, 16);
  __syncthreads();
  // S20: out = coarse + (g @ h_w3 + h_b3)
  if (tid < 64) {
    int q = tid >> 1, o = tid & 1;
    float acc = P.h_b3[o];
    const u16* rp = ab0 + q * 136;
#pragma unroll
    for (int c8 = 0; c8 < 8; ++c8) {
      half8_t v = *reinterpret_cast<const half8_t*>(rp + c8 * 8);
#pragma unroll
      for (int j = 0; j < 8; ++j) acc += (float)v[j] * P.h_w3[(c8 * 8 + j) * 2 + o];
    }
    P.out[(m0 + q) * 2 + o] = cb[q * 2 + o] + acc;
  }
}

extern "C" void kernel_launch(void* const* d_in, const int* in_sizes, int n_in,
                              void* d_out, int out_size, void* d_ws, size_t ws_size,
                              hipStream_t stream) {
  u16* wp = (u16*)d_ws;

  PackArgs pa;
  pa.src[0]  = (const float*)d_in[5];   // pp_w1
  pa.src[1]  = (const float*)d_in[7];   // pp_w2
  pa.src[2]  = (const float*)d_in[9];   // p8_w
  pa.src[3]  = (const float*)d_in[11];  // p16_w
  pa.src[4]  = (const float*)d_in[13];  // f1_ph_w
  pa.src[5]  = (const float*)d_in[16];  // f1_w1
  pa.src[6]  = (const float*)d_in[18];  // f1_w2
  pa.src[7]  = (const float*)d_in[22];  // f2_ph_w
  pa.src[8]  = (const float*)d_in[25];  // f2_w1
  pa.src[9]  = (const float*)d_in[27];  // f2_w2
  pa.src[10] = (const float*)d_in[31];  // h_w1
  pa.src[11] = (const float*)d_in[33];  // h_w2
  pa.dst = wp;
  pack_weights<<<512, 256, 0, stream>>>(pa);
  cvt_cl_f16<<<1024, 256, 0, stream>>>((const float*)d_in[1], wp + FT8_OFF, H8, W8);
  cvt_cl_f16<<<256, 256, 0, stream>>>((const float*)d_in[2], wp + FT16_OFF, H16, W16);

  KParams P;
  P.img = (const float*)d_in[0];
  P.coarse_flow = (const float*)d_in[3];
  P.qc = (const float*)d_in[4];
  P.wpk = wp; P.ft8 = wp + FT8_OFF; P.ft16 = wp + FT16_OFF;
  P.pp_b1 = (const float*)d_in[6];  P.pp_b2 = (const float*)d_in[8];
  P.p8_b = (const float*)d_in[10];  P.p16_b = (const float*)d_in[12];
  P.f1_ph_b = (const float*)d_in[14]; P.f1_gate = (const float*)d_in[15];
  P.f1_b1 = (const float*)d_in[17]; P.f1_b2 = (const float*)d_in[19];
  P.f1_ln_w = (const float*)d_in[20]; P.f1_ln_b = (const float*)d_in[21];
  P.f2_ph_b = (const float*)d_in[23]; P.f2_gate = (const float*)d_in[24];
  P.f2_b1 = (const float*)d_in[26]; P.f2_b2 = (const float*)d_in[28];
  P.f2_ln_w = (const float*)d_in[29]; P.f2_ln_b = (const float*)d_in[30];
  P.h_b1 = (const float*)d_in[32]; P.h_b2 = (const float*)d_in[34];
  P.h_w3 = (const float*)d_in[35]; P.h_b3 = (const float*)d_in[36];
  P.out = (float*)d_out;

  ifd_mfma<<<MTOT / MB, NT, 0, stream>>>(P);
}